// Round 4
// baseline (9427.584 us; speedup 1.0000x reference)
//
#include <hip/hip_runtime.h>
#include <hip/hip_bf16.h>
#include <hip/hip_fp16.h>

#define NN 50000
#define NE 800000
#define NP 50176          // 196*256 padded node count for scan
#define NBLK 196

#define E8(M) M(0) M(1) M(2) M(3) M(4) M(5) M(6) M(7)

__device__ __forceinline__ float us2f_bf16(unsigned short u){
    unsigned v = ((unsigned)u) << 16; float f; __builtin_memcpy(&f, &v, 4); return f;
}
__device__ __forceinline__ float us2f_f16(unsigned short u){
    __half h; __builtin_memcpy(&h, &u, 2); return __half2float(h);
}
// mode: 0=bf16, 1=f16, 2=fp32
__device__ __forceinline__ float ldf3(const void* p, size_t i, int mode){
    if (mode == 2) return ((const float*)p)[i];
    unsigned short u = ((const unsigned short*)p)[i];
    return (mode == 0) ? us2f_bf16(u) : us2f_f16(u);
}
__device__ __forceinline__ int ldi(const int* p, size_t j, int i64){
    return i64 ? p[2*j] : p[j];
}
__device__ __forceinline__ unsigned f2bf_rne(float f){
    unsigned u; __builtin_memcpy(&u, &f, 4);
    return (u + 0x7fffu + ((u >> 16) & 1u)) >> 16;
}
// broadcast lane l's value via v_readlane (VALU pipe -> SGPR, no LDS, no lgkmcnt)
__device__ __forceinline__ float rl(float v, int l){
    return __uint_as_float(__builtin_amdgcn_readlane(__float_as_uint(v), l));
}

// ---------------- sentinel fill (fp32 output) ----------------
__global__ void fill_k(float* __restrict__ out, int n, float cval){
    int i = blockIdx.x*256 + threadIdx.x;
    if (i < n) out[i] = cval;
}

// ---------------- probes (validated) ----------------
__global__ void probe_f_k(const unsigned short* __restrict__ hf, int* __restrict__ flags){
    __shared__ int cnt;
    if (threadIdx.x == 0) cnt = 0;
    __syncthreads();
    int c = 0;
    for (int idx = threadIdx.x; idx < 2048; idx += 256){
        int ex = (hf[2*idx] >> 7) & 0xFF;
        if (ex >= 118 && ex <= 131) c++;
    }
    atomicAdd(&cnt, c);
    __syncthreads();
    if (threadIdx.x == 0){
        int inb = cnt;
        int mode;
        if (inb >= 1536)      mode = 0;     // bf16
        else if (inb <= 205)  mode = 2;     // fp32
        else                  mode = 1;     // f16
        flags[0] = mode;
    }
}
__global__ void probe_i_k(const int* __restrict__ d, int* __restrict__ flags){
    __shared__ int nz;
    if (threadIdx.x == 0) nz = 0;
    __syncthreads();
    int c = 0;
    for (int idx = threadIdx.x; idx < 2048; idx += 256){
        if (d[2*idx + 1] != 0) c++;
    }
    atomicAdd(&nz, c);
    __syncthreads();
    if (threadIdx.x == 0) flags[1] = (nz < 100) ? 1 : 0;
}

// ---------------- weight conversion ----------------
__global__ void cvt_k(const void* __restrict__ src, float* __restrict__ dst, int n,
                      const int* __restrict__ flags){
    int m = flags[0];
    int i = blockIdx.x*256 + threadIdx.x;
    if (i < n) dst[i] = ldf3(src, i, m);
}

// ---------------- pack per-layer WC (edge transform) into bf16 pairs --------
// WCp[l*2048 + kk*64 + c] holds bf16(WC[2kk][c]) | bf16(WC[2kk+1][c])<<16
__global__ void packwc_k(const float* __restrict__ Wlc, unsigned* __restrict__ WCp){
    int i = blockIdx.x*256 + threadIdx.x;     // 0..8191
    int l = i >> 11, r = i & 2047;
    int kk = r >> 6, c = r & 63;
    const float* WC = Wlc + (size_t)l*5*4096 + 4*4096;
    unsigned lo = f2bf_rne(WC[(2*kk)*64 + c]);
    unsigned hi = f2bf_rne(WC[(2*kk+1)*64 + c]);
    WCp[i] = lo | (hi << 16);
}

// ---------------- node embedding: wave per node (validated) ----------------
__global__ __launch_bounds__(256) void embed_k(const void* __restrict__ hf,
        const float* __restrict__ W, const float* __restrict__ b,
        float* __restrict__ h, const int* __restrict__ flags){
    int f = flags[0];
    int t = threadIdx.x, c = t & 63;
    int i = blockIdx.x*4 + (t >> 6);
    float a = b[c];
    #pragma unroll
    for (int k=0;k<6;k++) a += ldf3(hf, (size_t)i*6+k, f) * W[k*64+c];
    h[(size_t)i*64+c] = a;
}

// ---------------- CSR build (counting sort by dst, validated) ----------------
__global__ void zero_cnt_k(int* __restrict__ cnt){
    int i = blockIdx.x*256 + threadIdx.x;
    cnt[i] = 0;
}
__global__ void hist_k(const int* __restrict__ dst, int* __restrict__ cnt,
                       const int* __restrict__ flags){
    int i64 = flags[1];
    int j = blockIdx.x*256 + threadIdx.x;
    atomicAdd(&cnt[ldi(dst, j, i64)], 1);
}
__global__ void scan1_k(const int* __restrict__ cnt, int* __restrict__ row_start,
                        int* __restrict__ bsum){
    __shared__ int s[256];
    int t = threadIdx.x;
    int i = blockIdx.x*256 + t;
    int v = cnt[i];
    s[t] = v; __syncthreads();
    #pragma unroll
    for (int off=1; off<256; off<<=1){
        int add = (t>=off) ? s[t-off] : 0;
        __syncthreads();
        s[t] += add;
        __syncthreads();
    }
    row_start[i] = s[t] - v;
    if (t==255) bsum[blockIdx.x] = s[255];
}
__global__ void scan2_k(const int* __restrict__ bsum, int* __restrict__ boff){
    __shared__ int s[256];
    int t = threadIdx.x;
    int v = (t < NBLK) ? bsum[t] : 0;
    s[t] = v; __syncthreads();
    #pragma unroll
    for (int off=1; off<256; off<<=1){
        int add = (t>=off) ? s[t-off] : 0;
        __syncthreads();
        s[t] += add;
        __syncthreads();
    }
    if (t < NBLK) boff[t] = s[t] - v;
}
__global__ void scan3_k(int* __restrict__ row_start, const int* __restrict__ boff,
                        int* __restrict__ cursor){
    int i = blockIdx.x*256 + threadIdx.x;
    int x = row_start[i] + boff[blockIdx.x];
    row_start[i] = x;
    cursor[i] = x;
}
__global__ void scatter_k(const int* __restrict__ dst, int* __restrict__ cursor,
                          int* __restrict__ perm, const int* __restrict__ flags){
    int i64 = flags[1];
    int j = blockIdx.x*256 + threadIdx.x;
    int d = ldi(dst, j, i64);
    int p = atomicAdd(&cursor[d], 1);
    perm[p] = j;
}

// ---------------- e init in CSR order + fused meta build ----------------
// meta[p] = src16 | ((dst&7) << 16), written into perm's own storage
// (each p is owned by exactly one wave: read perm[p] happens before the
// aliased write in program order of that wave — safe).
__global__ void einit_k(const void* __restrict__ ef, const float* __restrict__ Wee,
                        const float* __restrict__ bee, const int* perm,
                        int* meta, const int* __restrict__ src,
                        const int* __restrict__ dst,
                        float* __restrict__ e, const int* __restrict__ flags){
    int f = flags[0], i64 = flags[1];
    int tid = blockIdx.x*256 + threadIdx.x;
    int c = tid & 63, p = tid >> 6;
    int j = perm[p];
    float f0 = ldf3(ef, (size_t)j*2+0, f), f1 = ldf3(ef, (size_t)j*2+1, f);
    e[(size_t)p*64+c] = bee[c] + f0*Wee[c] + f1*Wee[64+c];
    if (c == 0)
        meta[p] = (ldi(src, j, i64) & 0xffff) | ((ldi(dst, j, i64) & 7) << 16);
    if (p < 8 && c == 1) meta[NE + p] = 0;
}

// ---------------- per-layer Eh|Bh interleaved table: wave per node ----------
__global__ __launch_bounds__(256) void node2_k(int l, const float* __restrict__ h,
        const float* __restrict__ Wlc, const float* __restrict__ blc,
        float* __restrict__ EB){
    int t = threadIdx.x, c = t & 63;
    int i = blockIdx.x*4 + (t >> 6);
    const float* WB = Wlc + (size_t)l*5*4096 + 4096;
    const float* WE = Wlc + (size_t)l*5*4096 + 3*4096;
    const float* bm = blc + (size_t)l*320;
    float hv = h[(size_t)i*64 + c];
    float bo = bm[64+c], eo = bm[192+c];
    #pragma unroll
    for (int k=0;k<64;k++){
        float hk = rl(hv, k);
        bo = fmaf(hk, WB[k*64+c], bo);
        eo = fmaf(hk, WE[k*64+c], eo);
    }
    EB[(size_t)i*128 + c]      = eo;   // Eh
    EB[(size_t)i*128 + 64 + c] = bo;   // Bh
}

// ---------------- fused GEMM-gate-scatter-update: 8 nodes per block ----------
// Readlane GEMM (R3 structure) on a register diet: one u32 meta[] load per
// edge (replaces srcp+nd8), 32-bit byte-offset gather addressing from a
// per-lane EB base, launch_bounds(256,5) pinning VGPR<=102 -> 5 waves/SIMD
// (20 waves/CU vs R3's 12). Named-scalar pipeline state only (~56 regs), so
// the cap cannot trigger array-style scratch demotion.
__global__ __launch_bounds__(256, 5) void gg_k(int l,
        float* __restrict__ e, float* __restrict__ h,
        const float* __restrict__ EB,
        const int* __restrict__ meta,
        const int* __restrict__ row_start,
        const float* __restrict__ Wlc, const float* __restrict__ blc,
        const unsigned* __restrict__ WCp){
    __shared__ unsigned WCs[2048];        // 8 KB  bf16-pair WC
    __shared__ float DhL[512];            // 2 KB
    __shared__ float ndN[512], ndD[512];  // 4 KB

    int t = threadIdx.x, c = t & 63, w = t >> 6;
    int i0 = blockIdx.x * 8;
    const float* WA = Wlc + (size_t)l*5*4096;
    const float* WD = WA + 2*4096;
    const float* bm = blc + (size_t)l*320;

    for (int idx=t; idx<2048; idx+=256) WCs[idx] = WCp[(l<<11) + idx];
    for (int idx=t; idx<512;  idx+=256){ ndN[idx]=0.0f; ndD[idx]=0.0f; }

    // Ah (regs), Dh (LDS) rows for the 8 nodes (wave w -> nodes w, w+4)
    float ah0, ah1;
    {
        float hv = h[(size_t)(i0+w)*64 + c];
        float a = bm[c], d = bm[128+c];
        #pragma unroll
        for (int k=0;k<64;k++){
            float hk = rl(hv, k);
            a = fmaf(hk, WA[k*64+c], a);
            d = fmaf(hk, WD[k*64+c], d);
        }
        ah0 = a; DhL[w*64+c] = d;
    }
    {
        int n = w + 4;
        float hv = h[(size_t)(i0+n)*64 + c];
        float a = bm[c], d = bm[128+c];
        #pragma unroll
        for (int k=0;k<64;k++){
            float hk = rl(hv, k);
            a = fmaf(hk, WA[k*64+c], a);
            d = fmaf(hk, WD[k*64+c], d);
        }
        ah1 = a; DhL[n*64+c] = d;
    }
    __syncthreads();

    int p0 = row_start[i0], pend = row_start[i0+8];
    float bC = bm[256+c];
    const char* ebB = (const char*)EB + (size_t)(4*c);   // per-lane EB base

    // wave-private tiles: wave w owns edges [p0+w*8 + 32k, +8)
    int pt = p0 + (w << 3);

    #define DQ(q) float pe##q = 0.0f; unsigned m##q = 0u;
    E8(DQ)
    #undef DQ

    if (pt < pend){
        const float* ep = e + (size_t)pt*64 + c;
        #define LD(q) pe##q = ep[q*64]; m##q = (unsigned)meta[pt+q];
        E8(LD)
        #undef LD
    }

    for (; pt < pend; pt += 32){
        int nv = pend - pt; if (nv > 8) nv = 8;

        // gathers for CURRENT tile (land during the GEMM below)
        #define DG(q) float ehv##q, bhv##q;
        E8(DG)
        #undef DG
        #define LG(q) { unsigned off = (m##q & 0xffffu) << 9; \
                        ehv##q = *(const float*)(ebB + off); \
                        bhv##q = *(const float*)(ebB + off + 256); }
        E8(LG)
        #undef LG

        // prefetch NEXT tile's e rows + meta into named scalars
        int pnt = pt + 32;
        #define DN(q) float pn##q = 0.0f; unsigned mn##q = 0u;
        E8(DN)
        #undef DN
        if (pnt < pend){
            const float* ep = e + (size_t)pnt*64 + c;
            #define LN(q) pn##q = ep[q*64]; mn##q = (unsigned)meta[pnt+q];
            E8(LN)
            #undef LN
        }

        // 8-edge x 64-ch GEMM: readlane broadcasts (SGPR) x bf16-unpacked WC
        #define DC(q) float ce##q = 0.0f;
        E8(DC)
        #undef DC
        #pragma unroll
        for (int kq=0; kq<16; kq++){
            unsigned u0 = WCs[(2*kq+0)*64 + c];
            unsigned u1 = WCs[(2*kq+1)*64 + c];
            float w0 = __uint_as_float(u0 << 16);
            float w1 = __uint_as_float(u0 & 0xffff0000u);
            float w2 = __uint_as_float(u1 << 16);
            float w3 = __uint_as_float(u1 & 0xffff0000u);
            #define GQ(q) { float a0 = rl(pe##q, 4*kq+0); \
                            float a1 = rl(pe##q, 4*kq+1); \
                            float a2 = rl(pe##q, 4*kq+2); \
                            float a3 = rl(pe##q, 4*kq+3); \
                ce##q = fmaf(a3, w3, fmaf(a2, w2, fmaf(a1, w1, fmaf(a0, w0, ce##q)))); }
            E8(GQ)
            #undef GQ
        }

        // gate + LDS num/den + e write (residual free in pe)
        #define GT(q) if (q < nv){ \
            int n = (int)(m##q >> 16); \
            float ehat = ce##q + bC + DhL[n*64+c] + ehv##q; \
            float sig = 1.0f/(1.0f + __expf(-ehat)); \
            atomicAdd(&ndN[n*64+c], sig * bhv##q); \
            atomicAdd(&ndD[n*64+c], sig); \
            e[(size_t)(pt+q)*64+c] = pe##q + fmaxf(ehat, 0.0f); }
        E8(GT)
        #undef GT

        #define RT(q) pe##q = pn##q; m##q = mn##q;
        E8(RT)
        #undef RT
    }
    __syncthreads();   // drain all waves' LDS atomics

    // fused h update for the block's 8 nodes
    {
        float hv = h[(size_t)(i0+w)*64 + c];
        float val = ah0 + ndN[w*64+c]/(ndD[w*64+c] + 1e-6f);
        h[(size_t)(i0+w)*64 + c] = hv + fmaxf(val, 0.0f);
    }
    {
        int n = w + 4;
        float hv = h[(size_t)(i0+n)*64 + c];
        float val = ah1 + ndN[n*64+c]/(ndD[n*64+c] + 1e-6f);
        h[(size_t)(i0+n)*64 + c] = hv + fmaxf(val, 0.0f);
    }
}

// ---------------- MLP head: wave per node (validated) ----------------
__global__ __launch_bounds__(256) void head_k(const float* __restrict__ h,
        const float* __restrict__ W1, const float* __restrict__ b1,
        const float* __restrict__ W2, const float* __restrict__ b2,
        float* __restrict__ out){
    int t = threadIdx.x, c = t & 63;
    int i = blockIdx.x*4 + (t >> 6);
    float hv = h[(size_t)i*64 + c];
    float z0 = b1[c], z1 = b1[64+c];
    #pragma unroll 8
    for (int k=0;k<64;k++){
        float hk = __shfl(hv, k);
        z0 += hk * W1[k*128+c];
        z1 += hk * W1[k*128+64+c];
    }
    z0 = fmaxf(z0, 0.0f); z1 = fmaxf(z1, 0.0f);
    float o0 = z0*W2[c*2+0] + z1*W2[(64+c)*2+0];
    float o1 = z0*W2[c*2+1] + z1*W2[(64+c)*2+1];
    #pragma unroll
    for (int off=32; off; off>>=1){
        o0 += __shfl_xor(o0, off);
        o1 += __shfl_xor(o1, off);
    }
    if (c == 0){
        out[(size_t)i*2+0] = -1.2f*tanhf(o0 + b2[0]);
        out[(size_t)i*2+1] = -1.2f*tanhf(o1 + b2[1]);
    }
}

extern "C" void kernel_launch(void* const* d_in, const int* in_sizes, int n_in,
                              void* d_out, int out_size, void* d_ws, size_t ws_size,
                              hipStream_t stream){
    float* out = (float*)d_out;
    int fill_blocks = (out_size + 255) / 256;

    if (n_in != 14){
        fill_k<<<fill_blocks, 256, 0, stream>>>(out, out_size, 0.25f);
        return;
    }
    const int exp_sizes[14] = {300000, 1600000, 800000, 800000, 384, 64, 128, 64,
                               81920, 1280, 8192, 128, 256, 2};
    bool sizes_ok = (out_size == 100000);
    for (int i=0;i<14;i++) if (in_sizes[i] != exp_sizes[i]) sizes_ok = false;
    if (!sizes_ok){
        fill_k<<<fill_blocks, 256, 0, stream>>>(out, out_size, 0.5f);
        return;
    }

    // ---- ws layout, ~247 MB (<= 250.1 known-good) ----
    size_t need = 0;
    size_t o_flags = need; need += 16;
    size_t o_rs   = need; need += (size_t)NP*4;
    size_t o_cur  = need; need += (size_t)NP*4;
    size_t o_bsum = need; need += (size_t)NBLK*4;
    size_t o_boff = need; need += (size_t)NBLK*4;
    size_t o_Weh  = need; need += 384ull*4;
    size_t o_beh  = need; need += 64ull*4;
    size_t o_Wee  = need; need += 128ull*4;
    size_t o_bee  = need; need += 64ull*4;
    size_t o_Wl   = need; need += 81920ull*4;
    size_t o_bl   = need; need += 1280ull*4;
    size_t o_W1   = need; need += 8192ull*4;
    size_t o_b1   = need; need += 128ull*4;
    size_t o_W2   = need; need += 256ull*4;
    size_t o_b2   = need; need += 2ull*4;
    size_t o_WCp  = need; need += 8192ull*4;
    need = (need + 255) & ~(size_t)255;
    size_t o_perm = need; need += (size_t)(NE+8)*4;   // perm, later reused as meta
    need = (need + 255) & ~(size_t)255;
    size_t o_h    = need; need += (size_t)NN*64*4;
    size_t o_EB   = need; need += (size_t)NN*128*4;
    size_t o_e    = need; need += (size_t)(NE+8)*64*4;   // +8 rows pad: no clamps
    if (ws_size < need){
        fill_k<<<fill_blocks, 256, 0, stream>>>(out, out_size, 0.75f);
        return;
    }

    char* p = (char*)d_ws;
    int*   flags = (int*)(p + o_flags);
    int*   row_start = (int*)(p + o_rs);
    int*   cursor    = (int*)(p + o_cur);
    int*   bsum = (int*)(p + o_bsum);
    int*   boff = (int*)(p + o_boff);
    float* Weh = (float*)(p + o_Weh);
    float* beh = (float*)(p + o_beh);
    float* Wee = (float*)(p + o_Wee);
    float* bee = (float*)(p + o_bee);
    float* Wlc = (float*)(p + o_Wl);
    float* blc = (float*)(p + o_bl);
    float* W1c = (float*)(p + o_W1);
    float* b1c = (float*)(p + o_b1);
    float* W2c = (float*)(p + o_W2);
    float* b2c = (float*)(p + o_b2);
    unsigned* WCp = (unsigned*)(p + o_WCp);
    int*   perm = (int*)(p + o_perm);       // reused as meta after einit
    float* h  = (float*)(p + o_h);
    float* EB = (float*)(p + o_EB);
    float* e  = (float*)(p + o_e);
    int* cnt = cursor;

    const int* src = (const int*)d_in[2];
    const int* dst = (const int*)d_in[3];

    probe_f_k<<<1, 256, 0, stream>>>((const unsigned short*)d_in[0], flags);
    probe_i_k<<<1, 256, 0, stream>>>(dst, flags);

    cvt_k<<<2, 256, 0, stream>>>(d_in[4], Weh, 384, flags);
    cvt_k<<<1, 256, 0, stream>>>(d_in[5], beh, 64, flags);
    cvt_k<<<1, 256, 0, stream>>>(d_in[6], Wee, 128, flags);
    cvt_k<<<1, 256, 0, stream>>>(d_in[7], bee, 64, flags);
    cvt_k<<<(81920+255)/256, 256, 0, stream>>>(d_in[8], Wlc, 81920, flags);
    cvt_k<<<5, 256, 0, stream>>>(d_in[9], blc, 1280, flags);
    cvt_k<<<32, 256, 0, stream>>>(d_in[10], W1c, 8192, flags);
    cvt_k<<<1, 256, 0, stream>>>(d_in[11], b1c, 128, flags);
    cvt_k<<<1, 256, 0, stream>>>(d_in[12], W2c, 256, flags);
    cvt_k<<<1, 256, 0, stream>>>(d_in[13], b2c, 2, flags);

    packwc_k<<<32, 256, 0, stream>>>(Wlc, WCp);

    embed_k<<<NN/4, 256, 0, stream>>>(d_in[0], Weh, beh, h, flags);

    zero_cnt_k<<<NBLK, 256, 0, stream>>>(cnt);
    hist_k<<<NE/256, 256, 0, stream>>>(dst, cnt, flags);
    scan1_k<<<NBLK, 256, 0, stream>>>(cnt, row_start, bsum);
    scan2_k<<<1, 256, 0, stream>>>(bsum, boff);
    scan3_k<<<NBLK, 256, 0, stream>>>(row_start, boff, cursor);
    scatter_k<<<NE/256, 256, 0, stream>>>(dst, cursor, perm, flags);

    // einit also builds meta[] in-place over perm[]
    einit_k<<<NE*64/256, 256, 0, stream>>>(d_in[1], Wee, bee, perm, perm, src, dst,
                                           e, flags);

    for (int l=0; l<4; l++){
        node2_k<<<NN/4, 256, 0, stream>>>(l, h, Wlc, blc, EB);
        gg_k<<<NN/8, 256, 0, stream>>>(l, e, h, EB, perm, row_start, Wlc, blc, WCp);
    }
    head_k<<<NN/4, 256, 0, stream>>>(h, W1c, b1c, W2c, b2c, out);
}

// Round 5
// 3413.029 us; speedup vs baseline: 2.7622x; 2.7622x over previous
//
#include <hip/hip_runtime.h>
#include <hip/hip_bf16.h>
#include <hip/hip_fp16.h>

#define NN 50000
#define NE 800000
#define NP 50176          // 196*256 padded node count for scan
#define NBLK 196

#define E8(M)  M(0) M(1) M(2) M(3) M(4) M(5) M(6) M(7)
#define E8B(M) M(8) M(9) M(10) M(11) M(12) M(13) M(14) M(15)
#define E16(M) E8(M) E8B(M)

typedef __attribute__((ext_vector_type(8))) short bfrag;   // 8 bf16 (4 VGPR)
typedef __attribute__((ext_vector_type(4))) float facc;    // 4 fp32 acc

__device__ __forceinline__ float us2f_bf16(unsigned short u){
    unsigned v = ((unsigned)u) << 16; float f; __builtin_memcpy(&f, &v, 4); return f;
}
__device__ __forceinline__ float us2f_f16(unsigned short u){
    __half h; __builtin_memcpy(&h, &u, 2); return __half2float(h);
}
// mode: 0=bf16, 1=f16, 2=fp32
__device__ __forceinline__ float ldf3(const void* p, size_t i, int mode){
    if (mode == 2) return ((const float*)p)[i];
    unsigned short u = ((const unsigned short*)p)[i];
    return (mode == 0) ? us2f_bf16(u) : us2f_f16(u);
}
__device__ __forceinline__ int ldi(const int* p, size_t j, int i64){
    return i64 ? p[2*j] : p[j];
}
__device__ __forceinline__ unsigned f2bf_rne(float f){
    unsigned u; __builtin_memcpy(&u, &f, 4);
    return (u + 0x7fffu + ((u >> 16) & 1u)) >> 16;
}
// broadcast lane l's value via v_readlane (VALU pipe -> SGPR, no LDS)
__device__ __forceinline__ float rl(float v, int l){
    return __uint_as_float(__builtin_amdgcn_readlane(__float_as_uint(v), l));
}

// ---------------- sentinel fill (fp32 output) ----------------
__global__ void fill_k(float* __restrict__ out, int n, float cval){
    int i = blockIdx.x*256 + threadIdx.x;
    if (i < n) out[i] = cval;
}

// ---------------- probes (validated) ----------------
__global__ void probe_f_k(const unsigned short* __restrict__ hf, int* __restrict__ flags){
    __shared__ int cnt;
    if (threadIdx.x == 0) cnt = 0;
    __syncthreads();
    int c = 0;
    for (int idx = threadIdx.x; idx < 2048; idx += 256){
        int ex = (hf[2*idx] >> 7) & 0xFF;
        if (ex >= 118 && ex <= 131) c++;
    }
    atomicAdd(&cnt, c);
    __syncthreads();
    if (threadIdx.x == 0){
        int inb = cnt;
        int mode;
        if (inb >= 1536)      mode = 0;     // bf16
        else if (inb <= 205)  mode = 2;     // fp32
        else                  mode = 1;     // f16
        flags[0] = mode;
    }
}
__global__ void probe_i_k(const int* __restrict__ d, int* __restrict__ flags){
    __shared__ int nz;
    if (threadIdx.x == 0) nz = 0;
    __syncthreads();
    int c = 0;
    for (int idx = threadIdx.x; idx < 2048; idx += 256){
        if (d[2*idx + 1] != 0) c++;
    }
    atomicAdd(&nz, c);
    __syncthreads();
    if (threadIdx.x == 0) flags[1] = (nz < 100) ? 1 : 0;
}

// ---------------- weight conversion ----------------
__global__ void cvt_k(const void* __restrict__ src, float* __restrict__ dst, int n,
                      const int* __restrict__ flags){
    int m = flags[0];
    int i = blockIdx.x*256 + threadIdx.x;
    if (i < n) dst[i] = ldf3(src, i, m);
}

// ---------------- pack per-layer WC into MFMA B-fragment layout (bf16) -----
// For 16x16x32_bf16: lane holds B[k][col] with k = s*32 + (lane>>4)*8 + j,
// col = ct*16 + (lane&15).  WBf[l*4096 + (ct*2+s)*512 + lane*8 + j]
__global__ void packb_k(const float* __restrict__ Wlc, unsigned short* __restrict__ WBf){
    int i = blockIdx.x*256 + threadIdx.x;     // 0..16383
    int l = i >> 12, r = i & 4095;
    int ct2s = r >> 9, lane = (r >> 3) & 63, j = r & 7;
    int ct = ct2s >> 1, s = ct2s & 1;
    int k  = s*32 + (lane >> 4)*8 + j;
    int col = ct*16 + (lane & 15);
    const float* WC = Wlc + (size_t)l*5*4096 + 4*4096;
    WBf[i] = (unsigned short)f2bf_rne(WC[k*64 + col]);
}

// ---------------- node embedding: wave per node (validated) ----------------
__global__ __launch_bounds__(256) void embed_k(const void* __restrict__ hf,
        const float* __restrict__ W, const float* __restrict__ b,
        float* __restrict__ h, const int* __restrict__ flags){
    int f = flags[0];
    int t = threadIdx.x, c = t & 63;
    int i = blockIdx.x*4 + (t >> 6);
    float a = b[c];
    #pragma unroll
    for (int k=0;k<6;k++) a += ldf3(hf, (size_t)i*6+k, f) * W[k*64+c];
    h[(size_t)i*64+c] = a;
}

// ---------------- CSR build (counting sort by dst, validated) ----------------
__global__ void zero_cnt_k(int* __restrict__ cnt){
    int i = blockIdx.x*256 + threadIdx.x;
    cnt[i] = 0;
}
__global__ void hist_k(const int* __restrict__ dst, int* __restrict__ cnt,
                       const int* __restrict__ flags){
    int i64 = flags[1];
    int j = blockIdx.x*256 + threadIdx.x;
    atomicAdd(&cnt[ldi(dst, j, i64)], 1);
}
__global__ void scan1_k(const int* __restrict__ cnt, int* __restrict__ row_start,
                        int* __restrict__ bsum){
    __shared__ int s[256];
    int t = threadIdx.x;
    int i = blockIdx.x*256 + t;
    int v = cnt[i];
    s[t] = v; __syncthreads();
    #pragma unroll
    for (int off=1; off<256; off<<=1){
        int add = (t>=off) ? s[t-off] : 0;
        __syncthreads();
        s[t] += add;
        __syncthreads();
    }
    row_start[i] = s[t] - v;
    if (t==255) bsum[blockIdx.x] = s[255];
}
__global__ void scan2_k(const int* __restrict__ bsum, int* __restrict__ boff){
    __shared__ int s[256];
    int t = threadIdx.x;
    int v = (t < NBLK) ? bsum[t] : 0;
    s[t] = v; __syncthreads();
    #pragma unroll
    for (int off=1; off<256; off<<=1){
        int add = (t>=off) ? s[t-off] : 0;
        __syncthreads();
        s[t] += add;
        __syncthreads();
    }
    if (t < NBLK) boff[t] = s[t] - v;
}
__global__ void scan3_k(int* __restrict__ row_start, const int* __restrict__ boff,
                        int* __restrict__ cursor){
    int i = blockIdx.x*256 + threadIdx.x;
    int x = row_start[i] + boff[blockIdx.x];
    row_start[i] = x;
    cursor[i] = x;
}
__global__ void scatter_k(const int* __restrict__ dst, int* __restrict__ cursor,
                          int* __restrict__ perm, const int* __restrict__ flags){
    int i64 = flags[1];
    int j = blockIdx.x*256 + threadIdx.x;
    int d = ldi(dst, j, i64);
    int p = atomicAdd(&cursor[d], 1);
    perm[p] = j;
}

// ---------------- e init in CSR order + fused meta build ----------------
// meta[p] = src16 | ((dst&7) << 16), written into perm's own storage.
__global__ void einit_k(const void* __restrict__ ef, const float* __restrict__ Wee,
                        const float* __restrict__ bee, const int* perm,
                        int* meta, const int* __restrict__ src,
                        const int* __restrict__ dst,
                        float* __restrict__ e, const int* __restrict__ flags){
    int f = flags[0], i64 = flags[1];
    int tid = blockIdx.x*256 + threadIdx.x;
    int c = tid & 63, p = tid >> 6;
    int j = perm[p];
    float f0 = ldf3(ef, (size_t)j*2+0, f), f1 = ldf3(ef, (size_t)j*2+1, f);
    e[(size_t)p*64+c] = bee[c] + f0*Wee[c] + f1*Wee[64+c];
    if (c == 0)
        meta[p] = (ldi(src, j, i64) & 0xffff) | ((ldi(dst, j, i64) & 7) << 16);
    if (p < 16 && c == 1) meta[NE + p] = 0;
}

// ---------------- per-layer Eh|Bh interleaved table: wave per node ----------
__global__ __launch_bounds__(256) void node2_k(int l, const float* __restrict__ h,
        const float* __restrict__ Wlc, const float* __restrict__ blc,
        float* __restrict__ EB){
    int t = threadIdx.x, c = t & 63;
    int i = blockIdx.x*4 + (t >> 6);
    const float* WB = Wlc + (size_t)l*5*4096 + 4096;
    const float* WE = Wlc + (size_t)l*5*4096 + 3*4096;
    const float* bm = blc + (size_t)l*320;
    float hv = h[(size_t)i*64 + c];
    float bo = bm[64+c], eo = bm[192+c];
    #pragma unroll
    for (int k=0;k<64;k++){
        float hk = rl(hv, k);
        bo = fmaf(hk, WB[k*64+c], bo);
        eo = fmaf(hk, WE[k*64+c], eo);
    }
    EB[(size_t)i*128 + c]      = eo;   // Eh
    EB[(size_t)i*128 + 64 + c] = bo;   // Bh
}

// ---------------- fused MFMA-GEMM-gate-scatter-update: 8 nodes per block ----
// 16-edge wave tiles. e rows (fp32, lane=c) staged into the wave-private LDS
// tile T, re-read in A-fragment order, converted to bf16, fed to
// v_mfma_f32_16x16x32_bf16 against pre-packed B-fragments (WBf). MFMA output
// (col=lane&15, row=(lane>>4)*4+reg) is written back to T and re-read in
// lane=c order, so the validated gate/atomic/write phase is unchanged.
__global__ __launch_bounds__(256) void gg_k(int l,
        float* __restrict__ e, float* __restrict__ h,
        const float* __restrict__ EB,
        const int* __restrict__ meta,
        const int* __restrict__ row_start,
        const float* __restrict__ Wlc, const float* __restrict__ blc,
        const unsigned short* __restrict__ WBf){
    __shared__ float T[4][16*65];          // 16.6 KB: wave-private transpose tile
    __shared__ float DhL[512];             // 2 KB
    __shared__ float ndN[512], ndD[512];   // 4 KB

    int t = threadIdx.x, c = t & 63, w = t >> 6;
    int r16 = c & 15, kb = c >> 4;
    int i0 = blockIdx.x * 8;
    const float* WA = Wlc + (size_t)l*5*4096;
    const float* WD = WA + 2*4096;
    const float* bm = blc + (size_t)l*320;

    for (int idx=t; idx<512; idx+=256){ ndN[idx]=0.0f; ndD[idx]=0.0f; }

    // B-fragments for this layer: 8 x short8, persistent in registers
    const unsigned short* WB = WBf + (l << 12) + c*8;
    bfrag B00 = *(const bfrag*)(WB + 0*512);   // ct0 s0
    bfrag B01 = *(const bfrag*)(WB + 1*512);   // ct0 s1
    bfrag B10 = *(const bfrag*)(WB + 2*512);
    bfrag B11 = *(const bfrag*)(WB + 3*512);
    bfrag B20 = *(const bfrag*)(WB + 4*512);
    bfrag B21 = *(const bfrag*)(WB + 5*512);
    bfrag B30 = *(const bfrag*)(WB + 6*512);
    bfrag B31 = *(const bfrag*)(WB + 7*512);

    // Ah (regs), Dh (LDS) rows for the 8 nodes (wave w -> nodes w, w+4)
    float ah0, ah1;
    {
        float hv = h[(size_t)(i0+w)*64 + c];
        float a = bm[c], d = bm[128+c];
        #pragma unroll
        for (int k=0;k<64;k++){
            float hk = rl(hv, k);
            a = fmaf(hk, WA[k*64+c], a);
            d = fmaf(hk, WD[k*64+c], d);
        }
        ah0 = a; DhL[w*64+c] = d;
    }
    {
        int n = w + 4;
        float hv = h[(size_t)(i0+n)*64 + c];
        float a = bm[c], d = bm[128+c];
        #pragma unroll
        for (int k=0;k<64;k++){
            float hk = rl(hv, k);
            a = fmaf(hk, WA[k*64+c], a);
            d = fmaf(hk, WD[k*64+c], d);
        }
        ah1 = a; DhL[n*64+c] = d;
    }
    __syncthreads();

    int p0 = row_start[i0], pend = row_start[i0+8];
    float bC = bm[256+c];
    const char* ebB = (const char*)EB + (size_t)(4*c);   // per-lane EB base
    float* Tw = T[w];
    int abase = r16*65 + kb*8;

    // wave-private tiles: wave w owns edges [p0+w*16 + 64k, +16)
    for (int pt = p0 + (w << 4); pt < pend; pt += 64){
        int nv = pend - pt; if (nv > 16) nv = 16;

        // meta + e rows (fp32, lane=c) for the 16 edges
        #define LM(q) unsigned m##q = (unsigned)meta[pt+q];
        E16(LM)
        #undef LM
        const float* ep = e + (size_t)pt*64 + c;
        #define LP(q) float pe##q = ep[q*64];
        E16(LP)
        #undef LP

        // gathers batch0 (q0..7): issue early, land under the MFMA phase
        #define DG(q) float ehv##q, bhv##q;
        E16(DG)
        #undef DG
        #define LG(q) { unsigned off = (m##q & 0xffffu) << 9; \
                        ehv##q = *(const float*)(ebB + off); \
                        bhv##q = *(const float*)(ebB + off + 256); }
        E8(LG)

        // stage e rows into T (lane=c), then read back in A-fragment order
        #define TW(q) Tw[q*65 + c] = pe##q;
        E16(TW)
        #undef TW
        bfrag a0v, a1v;
        #define AB(j) a0v[j] = (short)f2bf_rne(Tw[abase + j]); \
                      a1v[j] = (short)f2bf_rne(Tw[abase + 32 + j]);
        AB(0) AB(1) AB(2) AB(3) AB(4) AB(5) AB(6) AB(7)
        #undef AB

        // 16 edges x 64 ch x K=64: 8 MFMAs
        facc ac0 = {0.f,0.f,0.f,0.f}, ac1 = {0.f,0.f,0.f,0.f};
        facc ac2 = {0.f,0.f,0.f,0.f}, ac3 = {0.f,0.f,0.f,0.f};
        ac0 = __builtin_amdgcn_mfma_f32_16x16x32_bf16(a0v, B00, ac0, 0, 0, 0);
        ac1 = __builtin_amdgcn_mfma_f32_16x16x32_bf16(a0v, B10, ac1, 0, 0, 0);
        ac2 = __builtin_amdgcn_mfma_f32_16x16x32_bf16(a0v, B20, ac2, 0, 0, 0);
        ac3 = __builtin_amdgcn_mfma_f32_16x16x32_bf16(a0v, B30, ac3, 0, 0, 0);
        ac0 = __builtin_amdgcn_mfma_f32_16x16x32_bf16(a1v, B01, ac0, 0, 0, 0);
        ac1 = __builtin_amdgcn_mfma_f32_16x16x32_bf16(a1v, B11, ac1, 0, 0, 0);
        ac2 = __builtin_amdgcn_mfma_f32_16x16x32_bf16(a1v, B21, ac2, 0, 0, 0);
        ac3 = __builtin_amdgcn_mfma_f32_16x16x32_bf16(a1v, B31, ac3, 0, 0, 0);

        // gathers batch1 (q8..15) land under the transpose
        E8B(LG)
        #undef LG

        // acc -> T (C/D layout: row=(kb*4+r), col=ct*16+r16), then lane=c read
        #define TA(ct) Tw[(kb*4+0)*65 + ct*16 + r16] = ac##ct[0]; \
                       Tw[(kb*4+1)*65 + ct*16 + r16] = ac##ct[1]; \
                       Tw[(kb*4+2)*65 + ct*16 + r16] = ac##ct[2]; \
                       Tw[(kb*4+3)*65 + ct*16 + r16] = ac##ct[3];
        TA(0) TA(1) TA(2) TA(3)
        #undef TA
        #define CE(q) float ce##q = Tw[q*65 + c];
        E16(CE)
        #undef CE

        // gate + LDS num/den + e write (residual free in pe)
        #define GT(q) if (q < nv){ \
            int n = (int)(m##q >> 16); \
            float ehat = ce##q + bC + DhL[n*64+c] + ehv##q; \
            float sig = 1.0f/(1.0f + __expf(-ehat)); \
            atomicAdd(&ndN[n*64+c], sig * bhv##q); \
            atomicAdd(&ndD[n*64+c], sig); \
            e[(size_t)(pt+q)*64+c] = pe##q + fmaxf(ehat, 0.0f); }
        E16(GT)
        #undef GT
    }
    __syncthreads();   // drain all waves' LDS atomics

    // fused h update for the block's 8 nodes
    {
        float hv = h[(size_t)(i0+w)*64 + c];
        float val = ah0 + ndN[w*64+c]/(ndD[w*64+c] + 1e-6f);
        h[(size_t)(i0+w)*64 + c] = hv + fmaxf(val, 0.0f);
    }
    {
        int n = w + 4;
        float hv = h[(size_t)(i0+n)*64 + c];
        float val = ah1 + ndN[n*64+c]/(ndD[n*64+c] + 1e-6f);
        h[(size_t)(i0+n)*64 + c] = hv + fmaxf(val, 0.0f);
    }
}

// ---------------- MLP head: wave per node (validated) ----------------
__global__ __launch_bounds__(256) void head_k(const float* __restrict__ h,
        const float* __restrict__ W1, const float* __restrict__ b1,
        const float* __restrict__ W2, const float* __restrict__ b2,
        float* __restrict__ out){
    int t = threadIdx.x, c = t & 63;
    int i = blockIdx.x*4 + (t >> 6);
    float hv = h[(size_t)i*64 + c];
    float z0 = b1[c], z1 = b1[64+c];
    #pragma unroll 8
    for (int k=0;k<64;k++){
        float hk = __shfl(hv, k);
        z0 += hk * W1[k*128+c];
        z1 += hk * W1[k*128+64+c];
    }
    z0 = fmaxf(z0, 0.0f); z1 = fmaxf(z1, 0.0f);
    float o0 = z0*W2[c*2+0] + z1*W2[(64+c)*2+0];
    float o1 = z0*W2[c*2+1] + z1*W2[(64+c)*2+1];
    #pragma unroll
    for (int off=32; off; off>>=1){
        o0 += __shfl_xor(o0, off);
        o1 += __shfl_xor(o1, off);
    }
    if (c == 0){
        out[(size_t)i*2+0] = -1.2f*tanhf(o0 + b2[0]);
        out[(size_t)i*2+1] = -1.2f*tanhf(o1 + b2[1]);
    }
}

extern "C" void kernel_launch(void* const* d_in, const int* in_sizes, int n_in,
                              void* d_out, int out_size, void* d_ws, size_t ws_size,
                              hipStream_t stream){
    float* out = (float*)d_out;
    int fill_blocks = (out_size + 255) / 256;

    if (n_in != 14){
        fill_k<<<fill_blocks, 256, 0, stream>>>(out, out_size, 0.25f);
        return;
    }
    const int exp_sizes[14] = {300000, 1600000, 800000, 800000, 384, 64, 128, 64,
                               81920, 1280, 8192, 128, 256, 2};
    bool sizes_ok = (out_size == 100000);
    for (int i=0;i<14;i++) if (in_sizes[i] != exp_sizes[i]) sizes_ok = false;
    if (!sizes_ok){
        fill_k<<<fill_blocks, 256, 0, stream>>>(out, out_size, 0.5f);
        return;
    }

    // ---- ws layout, ~247 MB (<= 250.1 known-good) ----
    size_t need = 0;
    size_t o_flags = need; need += 16;
    size_t o_rs   = need; need += (size_t)NP*4;
    size_t o_cur  = need; need += (size_t)NP*4;
    size_t o_bsum = need; need += (size_t)NBLK*4;
    size_t o_boff = need; need += (size_t)NBLK*4;
    size_t o_Weh  = need; need += 384ull*4;
    size_t o_beh  = need; need += 64ull*4;
    size_t o_Wee  = need; need += 128ull*4;
    size_t o_bee  = need; need += 64ull*4;
    size_t o_Wl   = need; need += 81920ull*4;
    size_t o_bl   = need; need += 1280ull*4;
    size_t o_W1   = need; need += 8192ull*4;
    size_t o_b1   = need; need += 128ull*4;
    size_t o_W2   = need; need += 256ull*4;
    size_t o_b2   = need; need += 2ull*4;
    size_t o_WBf  = need; need += 16384ull*2;   // MFMA B-fragments, 4 layers
    need = (need + 255) & ~(size_t)255;
    size_t o_perm = need; need += (size_t)(NE+16)*4;   // perm, reused as meta
    need = (need + 255) & ~(size_t)255;
    size_t o_h    = need; need += (size_t)NN*64*4;
    size_t o_EB   = need; need += (size_t)NN*128*4;
    size_t o_e    = need; need += (size_t)(NE+16)*64*4;  // +16 rows pad
    if (ws_size < need){
        fill_k<<<fill_blocks, 256, 0, stream>>>(out, out_size, 0.75f);
        return;
    }

    char* p = (char*)d_ws;
    int*   flags = (int*)(p + o_flags);
    int*   row_start = (int*)(p + o_rs);
    int*   cursor    = (int*)(p + o_cur);
    int*   bsum = (int*)(p + o_bsum);
    int*   boff = (int*)(p + o_boff);
    float* Weh = (float*)(p + o_Weh);
    float* beh = (float*)(p + o_beh);
    float* Wee = (float*)(p + o_Wee);
    float* bee = (float*)(p + o_bee);
    float* Wlc = (float*)(p + o_Wl);
    float* blc = (float*)(p + o_bl);
    float* W1c = (float*)(p + o_W1);
    float* b1c = (float*)(p + o_b1);
    float* W2c = (float*)(p + o_W2);
    float* b2c = (float*)(p + o_b2);
    unsigned short* WBf = (unsigned short*)(p + o_WBf);
    int*   perm = (int*)(p + o_perm);       // reused as meta after einit
    float* h  = (float*)(p + o_h);
    float* EB = (float*)(p + o_EB);
    float* e  = (float*)(p + o_e);
    int* cnt = cursor;

    const int* src = (const int*)d_in[2];
    const int* dst = (const int*)d_in[3];

    probe_f_k<<<1, 256, 0, stream>>>((const unsigned short*)d_in[0], flags);
    probe_i_k<<<1, 256, 0, stream>>>(dst, flags);

    cvt_k<<<2, 256, 0, stream>>>(d_in[4], Weh, 384, flags);
    cvt_k<<<1, 256, 0, stream>>>(d_in[5], beh, 64, flags);
    cvt_k<<<1, 256, 0, stream>>>(d_in[6], Wee, 128, flags);
    cvt_k<<<1, 256, 0, stream>>>(d_in[7], bee, 64, flags);
    cvt_k<<<(81920+255)/256, 256, 0, stream>>>(d_in[8], Wlc, 81920, flags);
    cvt_k<<<5, 256, 0, stream>>>(d_in[9], blc, 1280, flags);
    cvt_k<<<32, 256, 0, stream>>>(d_in[10], W1c, 8192, flags);
    cvt_k<<<1, 256, 0, stream>>>(d_in[11], b1c, 128, flags);
    cvt_k<<<1, 256, 0, stream>>>(d_in[12], W2c, 256, flags);
    cvt_k<<<1, 256, 0, stream>>>(d_in[13], b2c, 2, flags);

    packb_k<<<64, 256, 0, stream>>>(Wlc, WBf);

    embed_k<<<NN/4, 256, 0, stream>>>(d_in[0], Weh, beh, h, flags);

    zero_cnt_k<<<NBLK, 256, 0, stream>>>(cnt);
    hist_k<<<NE/256, 256, 0, stream>>>(dst, cnt, flags);
    scan1_k<<<NBLK, 256, 0, stream>>>(cnt, row_start, bsum);
    scan2_k<<<1, 256, 0, stream>>>(bsum, boff);
    scan3_k<<<NBLK, 256, 0, stream>>>(row_start, boff, cursor);
    scatter_k<<<NE/256, 256, 0, stream>>>(dst, cursor, perm, flags);

    // einit also builds meta[] in-place over perm[]
    einit_k<<<NE*64/256, 256, 0, stream>>>(d_in[1], Wee, bee, perm, perm, src, dst,
                                           e, flags);

    for (int l=0; l<4; l++){
        node2_k<<<NN/4, 256, 0, stream>>>(l, h, Wlc, blc, EB);
        gg_k<<<NN/8, 256, 0, stream>>>(l, e, h, EB, perm, row_start, Wlc, blc, WBf);
    }
    head_k<<<NN/4, 256, 0, stream>>>(h, W1c, b1c, W2c, b2c, out);
}